// Round 1
// baseline (1875.246 us; speedup 1.0000x reference)
//
#include <hip/hip_runtime.h>

// Problem constants (fixed by reference setup_inputs)
#define B   4
#define C   64      // input channels
#define D   64      // dims per head of q/k/v
#define NN  25      // angRes*angRes angular positions
#define HW  4096    // h*w
#define F   (D*HW)  // 262144 feature dim (d,h,w) flattened

#define NG        5      // n-rows per sdot block (25 = 5*5)
#define FCHUNK_S  8192   // f elems per sdot block
#define FCHUNK_N  16384  // f elems per norms block

typedef unsigned short ushort_t;
typedef unsigned int   uint_t;

static __device__ __forceinline__ ushort_t f2bf(float f) {
    uint_t u = __float_as_uint(f);
    u += 0x7FFFu + ((u >> 16) & 1u);   // round-to-nearest-even
    return (ushort_t)(u >> 16);
}

static __device__ __forceinline__ void bf8_to_f(const uint4 v, float* f) {
    f[0] = __uint_as_float(v.x << 16); f[1] = __uint_as_float(v.x & 0xffff0000u);
    f[2] = __uint_as_float(v.y << 16); f[3] = __uint_as_float(v.y & 0xffff0000u);
    f[4] = __uint_as_float(v.z << 16); f[5] = __uint_as_float(v.z & 0xffff0000u);
    f[6] = __uint_as_float(v.w << 16); f[7] = __uint_as_float(v.w & 0xffff0000u);
}

// ---- K0: zero the S/qq/kk accumulators (they live at head of d_out) ----
__global__ void k_zero(float* acc) {
    int i = blockIdx.x * 256 + threadIdx.x;
    if (i < 2700) acc[i] = 0.f;   // S 2500 + qq 100 + kk 100
}

// ---- K1: Q,K projection. grid (HW/256, NN, B), 256 thr. thread <-> position p.
// Q[b][n][f] with f = d*HW + p  (matches reference flat() layout), stored bf16.
__global__ void k_qkproj(const float* __restrict__ x, const float* __restrict__ W,
                         ushort_t* __restrict__ Q, ushort_t* __restrict__ K) {
    const int p = blockIdx.x * 256 + threadIdx.x;
    const int n = blockIdx.y, b = blockIdx.z;
    const float* xb = x + ((size_t)(b * C) * NN + n) * HW + p; // x[b][c][n][p]
    float xr[C];
#pragma unroll
    for (int c = 0; c < C; ++c) xr[c] = xb[(size_t)c * NN * HW];
    const float* Wq = W;            // W[0:64]   rows
    const float* Wk = W + D * C;    // W[64:128] rows
    const size_t obase = ((size_t)(b * NN + n) * D) * HW + p;
    for (int d = 0; d < D; ++d) {
        float qa = 0.f, ka = 0.f;
#pragma unroll
        for (int c = 0; c < C; ++c) {
            qa += Wq[d * C + c] * xr[c];   // uniform -> s_load
            ka += Wk[d * C + c] * xr[c];
        }
        Q[obase + (size_t)d * HW] = f2bf(qa);
        K[obase + (size_t)d * HW] = f2bf(ka);
    }
}

// ---- K2a: S[n][m] += Q[n,f]*K[m,f] over f-chunk. grid (F/FCHUNK_S, NN/NG, B).
__global__ void k_sdot(const ushort_t* __restrict__ Q, const ushort_t* __restrict__ K,
                       float* __restrict__ S) {
    const int t  = threadIdx.x;
    const int n0 = blockIdx.y * NG;
    const int b  = blockIdx.z;
    const size_t fbase = (size_t)blockIdx.x * FCHUNK_S;
    const ushort_t* Qb = Q + (size_t)b * NN * F;
    const ushort_t* Kb = K + (size_t)b * NN * F;

    float acc[NG][NN];
#pragma unroll
    for (int g = 0; g < NG; ++g)
#pragma unroll
        for (int m = 0; m < NN; ++m) acc[g][m] = 0.f;

    for (int it = 0; it < FCHUNK_S / (256 * 8); ++it) {
        const size_t f = fbase + ((size_t)it * 256 + t) * 8;
        float qf[NG][8];
#pragma unroll
        for (int g = 0; g < NG; ++g) {
            uint4 qv = *(const uint4*)(Qb + (size_t)(n0 + g) * F + f);
            bf8_to_f(qv, qf[g]);
        }
#pragma unroll
        for (int m = 0; m < NN; ++m) {
            uint4 kv = *(const uint4*)(Kb + (size_t)m * F + f);
            float kf[8]; bf8_to_f(kv, kf);
#pragma unroll
            for (int g = 0; g < NG; ++g)
#pragma unroll
                for (int j = 0; j < 8; ++j) acc[g][m] += qf[g][j] * kf[j];
        }
    }
    // per-wave butterfly reduce, lane0 atomics
#pragma unroll
    for (int g = 0; g < NG; ++g)
#pragma unroll
        for (int m = 0; m < NN; ++m) {
            float v = acc[g][m];
            for (int off = 32; off > 0; off >>= 1) v += __shfl_xor(v, off);
            if ((t & 63) == 0)
                atomicAdd(&S[((size_t)b * NN + n0 + g) * NN + m], v);
        }
}

// ---- K2b: qq[n] = sum Q^2, kk[m] = sum K^2. grid (F/FCHUNK_N, 2*NN, B).
__global__ void k_norms(const ushort_t* __restrict__ Q, const ushort_t* __restrict__ K,
                        float* __restrict__ qq, float* __restrict__ kk) {
    const int t = threadIdx.x;
    const int r = blockIdx.y, b = blockIdx.z;
    const ushort_t* src = (r < NN) ? (Q + ((size_t)b * NN + r) * F)
                                   : (K + ((size_t)b * NN + (r - NN)) * F);
    float* dst = (r < NN) ? &qq[b * NN + r] : &kk[b * NN + (r - NN)];
    float a = 0.f;
    for (int it = 0; it < FCHUNK_N / (256 * 8); ++it) {
        const size_t f = (size_t)blockIdx.x * FCHUNK_N + ((size_t)it * 256 + t) * 8;
        uint4 v = *(const uint4*)(src + f);
        float vf[8]; bf8_to_f(v, vf);
#pragma unroll
        for (int j = 0; j < 8; ++j) a += vf[j] * vf[j];
    }
    for (int off = 32; off > 0; off >>= 1) a += __shfl_xor(a, off);
    if ((t & 63) == 0) atomicAdd(dst, a);
}

// ---- K3: normalize logits + softmax over m. grid (B), 64 thr (25 active).
__global__ void k_softmax(const float* __restrict__ S, const float* __restrict__ qq,
                          const float* __restrict__ kk, float* __restrict__ att) {
    const int b = blockIdx.x, n = threadIdx.x;
    if (n >= NN) return;
    const float qn = fmaxf(sqrtf(qq[b * NN + n]), 1e-12f);
    float l[NN], mx = -1e30f;
#pragma unroll
    for (int m = 0; m < NN; ++m) {
        const float km = fmaxf(sqrtf(kk[b * NN + m]), 1e-12f);
        l[m] = S[((size_t)b * NN + n) * NN + m] / (qn * km);
        mx = fmaxf(mx, l[m]);
    }
    float s = 0.f;
#pragma unroll
    for (int m = 0; m < NN; ++m) { l[m] = expf(l[m] - mx); s += l[m]; }
    const float inv = 1.f / s;
#pragma unroll
    for (int m = 0; m < NN; ++m) att[((size_t)b * NN + n) * NN + m] = l[m] * inv;
}

// ---- K4a: xa[b,c,n,p] = sum_m att[n,m] * x[b,c,m,p]. grid (HW/256, C, B).
__global__ void k_mix(const float* __restrict__ x, const float* __restrict__ att,
                      float* __restrict__ xa) {
    const int p = blockIdx.x * 256 + threadIdx.x;
    const int c = blockIdx.y, b = blockIdx.z;
    const float* xb = x + ((size_t)(b * C + c) * NN) * HW + p;
    float xm[NN];
#pragma unroll
    for (int m = 0; m < NN; ++m) xm[m] = xb[(size_t)m * HW];
    const float* ab = att + (size_t)b * NN * NN;
    for (int n = 0; n < NN; ++n) {
        float a = 0.f;
#pragma unroll
        for (int m = 0; m < NN; ++m) a += ab[n * NN + m] * xm[m];  // att uniform -> s_load
        xa[((size_t)(b * C + c) * NN + n) * HW + p] = a;
    }
}

// ---- K4b: out[b,d,n,p] = sum_c Wv[d,c] * xa[b,c,n,p]. grid (HW/256, NN, B).
__global__ void k_vproj(const float* __restrict__ xa, const float* __restrict__ W,
                        float* __restrict__ out) {
    const int p = blockIdx.x * 256 + threadIdx.x;
    const int n = blockIdx.y, b = blockIdx.z;
    const float* Wv = W + 2 * D * C;   // W[128:192] rows
    const float* xb = xa + ((size_t)(b * C) * NN + n) * HW + p;
    float xr[C];
#pragma unroll
    for (int c = 0; c < C; ++c) xr[c] = xb[(size_t)c * NN * HW];
    for (int d = 0; d < D; ++d) {
        float a = 0.f;
#pragma unroll
        for (int c = 0; c < C; ++c) a += Wv[d * C + c] * xr[c];
        out[((size_t)(b * D + d) * NN + n) * HW + p] = a;
    }
}

extern "C" void kernel_launch(void* const* d_in, const int* in_sizes, int n_in,
                              void* d_out, int out_size, void* d_ws, size_t ws_size,
                              hipStream_t stream) {
    const float* x = (const float*)d_in[0];
    const float* W = (const float*)d_in[1];
    float* outf = (float*)d_out;

    // ws: [ Q bf16 52.4MB | K bf16 52.4MB ], later reused as xa fp32 (104.86MB)
    ushort_t* Q  = (ushort_t*)d_ws;
    ushort_t* K  = Q + (size_t)B * NN * F;
    float*    xa = (float*)d_ws;

    // tiny accumulators live at head of d_out (dead until k_vproj rewrites all)
    float* S   = outf;          // 4*25*25
    float* qq  = outf + 2500;   // 4*25
    float* kk  = outf + 2600;   // 4*25
    float* att = outf + 2700;   // 4*25*25

    k_zero   <<<dim3(11),                    256, 0, stream>>>(outf);
    k_qkproj <<<dim3(HW/256, NN, B),         256, 0, stream>>>(x, W, Q, K);
    k_sdot   <<<dim3(F/FCHUNK_S, NN/NG, B),  256, 0, stream>>>(Q, K, S);
    k_norms  <<<dim3(F/FCHUNK_N, 2*NN, B),   256, 0, stream>>>(Q, K, qq, kk);
    k_softmax<<<dim3(B),                      64, 0, stream>>>(S, qq, kk, att);
    k_mix    <<<dim3(HW/256, C, B),          256, 0, stream>>>(x, att, xa);
    k_vproj  <<<dim3(HW/256, NN, B),         256, 0, stream>>>(xa, W, outf);
}

// Round 2
// 640.062 us; speedup vs baseline: 2.9298x; 2.9298x over previous
//
#include <hip/hip_runtime.h>

// Problem constants (fixed by reference setup_inputs)
#define B   4
#define C   64      // input channels
#define D   64      // dims per head of q/k/v
#define NN  25      // angRes*angRes angular positions
#define HW  4096    // h*w
#define F   (D*HW)  // 262144 feature dim (d,h,w) flattened

#define SW  512     // f elems per wave in k_sqk (4 waves/block -> 2048 per block)

typedef unsigned short ushort_t;
typedef unsigned int   uint_t;
typedef __attribute__((ext_vector_type(8)))  short  short8;   // 8 bf16 (4 VGPRs)
typedef __attribute__((ext_vector_type(16))) float  floatx16; // MFMA 32x32 accum

static __device__ __forceinline__ ushort_t f2bf(float f) {
    uint_t u = __float_as_uint(f);
    u += 0x7FFFu + ((u >> 16) & 1u);   // round-to-nearest-even
    return (ushort_t)(u >> 16);
}

// ---- K0: zero the S/qq/kk accumulators (they live at head of d_out) ----
__global__ void k_zero(float* acc) {
    int i = blockIdx.x * 256 + threadIdx.x;
    if (i < 2700) acc[i] = 0.f;   // S 2500 + qq 100 + kk 100
}

// ---- K1: Q,K projection + fused norm accumulation.
// grid (HW/256, NN, B), 256 thr. Q[b][n][f], f = d*HW + p (reference flat()), bf16.
__global__ void k_qkproj(const float* __restrict__ x, const float* __restrict__ W,
                         ushort_t* __restrict__ Q, ushort_t* __restrict__ K,
                         float* __restrict__ qq, float* __restrict__ kk) {
    const int p = blockIdx.x * 256 + threadIdx.x;
    const int n = blockIdx.y, b = blockIdx.z;
    const float* xb = x + ((size_t)(b * C) * NN + n) * HW + p; // x[b][c][n][p]
    float xr[C];
#pragma unroll
    for (int c = 0; c < C; ++c) xr[c] = xb[(size_t)c * NN * HW];
    const float* Wq = W;            // W[0:64]   rows
    const float* Wk = W + D * C;    // W[64:128] rows
    const size_t obase = ((size_t)(b * NN + n) * D) * HW + p;
    float qn = 0.f, kn = 0.f;
    for (int d = 0; d < D; ++d) {
        float qa = 0.f, ka = 0.f;
#pragma unroll
        for (int c = 0; c < C; ++c) {
            qa += Wq[d * C + c] * xr[c];   // uniform -> s_load
            ka += Wk[d * C + c] * xr[c];
        }
        qn += qa * qa; kn += ka * ka;      // fp32 norms, pre-rounding (matches ref)
        Q[obase + (size_t)d * HW] = f2bf(qa);
        K[obase + (size_t)d * HW] = f2bf(ka);
    }
    // wave-reduce the norm partials, one atomic per wave
    for (int off = 32; off > 0; off >>= 1) {
        qn += __shfl_xor(qn, off);
        kn += __shfl_xor(kn, off);
    }
    if ((threadIdx.x & 63) == 0) {
        atomicAdd(&qq[b * NN + n], qn);
        atomicAdd(&kk[b * NN + n], kn);
    }
}

// ---- K2: S[n][m] += sum_f Q[n,f]*K[m,f] via one 32x32x16 bf16 MFMA tile.
// grid (F/(4*SW), B), 256 thr = 4 waves, each wave owns SW f-elems.
// Pad rows/cols 25..31 clamp to 24: they only feed discarded output rows/cols.
__global__ void k_sqk(const ushort_t* __restrict__ Q, const ushort_t* __restrict__ K,
                      float* __restrict__ S) {
    const int t  = threadIdx.x;
    const int wv = t >> 6, ln = t & 63;
    const int b  = blockIdx.y;
    const int row  = ln & 31;
    const int rowc = (row < NN) ? row : (NN - 1);   // clamp pad rows
    const int kh   = (ln >> 5) * 8;                 // k-half offset
    const size_t f0 = (size_t)blockIdx.x * (4 * SW) + (size_t)wv * SW;
    const ushort_t* Qp = Q + ((size_t)b * NN + rowc) * F + f0 + kh;
    const ushort_t* Kp = K + ((size_t)b * NN + rowc) * F + f0 + kh;

    floatx16 acc;
#pragma unroll
    for (int r = 0; r < 16; ++r) acc[r] = 0.f;

    for (int s = 0; s < SW / 16; ++s) {
        short8 aq = *(const short8*)(Qp + s * 16);  // A[row][k] : 8 contig bf16
        short8 bk = *(const short8*)(Kp + s * 16);  // B[k][col] : K row 'col'
        acc = __builtin_amdgcn_mfma_f32_32x32x16_bf16(aq, bk, acc, 0, 0, 0);
    }

    // cross-wave reduce in LDS (stride 17 -> conflict-free), then atomics
    __shared__ float redS[4][64][17];
#pragma unroll
    for (int r = 0; r < 16; ++r) redS[wv][ln][r] = acc[r];
    __syncthreads();
    if (wv == 0) {
#pragma unroll
        for (int r = 0; r < 16; ++r) {
            float v = redS[0][ln][r] + redS[1][ln][r] + redS[2][ln][r] + redS[3][ln][r];
            const int srow = (r & 3) + 8 * (r >> 2) + 4 * (ln >> 5); // C/D: m74/m101
            const int scol = ln & 31;
            if (srow < NN && scol < NN)
                atomicAdd(&S[((size_t)b * NN + srow) * NN + scol], v);
        }
    }
}

// ---- K3: normalize logits + softmax over m. grid (B), 64 thr (25 active).
__global__ void k_softmax(const float* __restrict__ S, const float* __restrict__ qq,
                          const float* __restrict__ kk, float* __restrict__ att) {
    const int b = blockIdx.x, n = threadIdx.x;
    if (n >= NN) return;
    const float qn = fmaxf(sqrtf(qq[b * NN + n]), 1e-12f);
    float l[NN], mx = -1e30f;
#pragma unroll
    for (int m = 0; m < NN; ++m) {
        const float km = fmaxf(sqrtf(kk[b * NN + m]), 1e-12f);
        l[m] = S[((size_t)b * NN + n) * NN + m] / (qn * km);
        mx = fmaxf(mx, l[m]);
    }
    float s = 0.f;
#pragma unroll
    for (int m = 0; m < NN; ++m) { l[m] = expf(l[m] - mx); s += l[m]; }
    const float inv = 1.f / s;
#pragma unroll
    for (int m = 0; m < NN; ++m) att[((size_t)b * NN + n) * NN + m] = l[m] * inv;
}

// ---- K4a: xa[b,c,n,p] = sum_m att[n,m] * x[b,c,m,p]. grid (HW/256, C, B).
__global__ void k_mix(const float* __restrict__ x, const float* __restrict__ att,
                      float* __restrict__ xa) {
    const int p = blockIdx.x * 256 + threadIdx.x;
    const int c = blockIdx.y, b = blockIdx.z;
    const float* xb = x + ((size_t)(b * C + c) * NN) * HW + p;
    float xm[NN];
#pragma unroll
    for (int m = 0; m < NN; ++m) xm[m] = xb[(size_t)m * HW];
    const float* ab = att + (size_t)b * NN * NN;
    for (int n = 0; n < NN; ++n) {
        float a = 0.f;
#pragma unroll
        for (int m = 0; m < NN; ++m) a += ab[n * NN + m] * xm[m];  // att uniform -> s_load
        xa[((size_t)(b * C + c) * NN + n) * HW + p] = a;
    }
}

// ---- K4b: out[b,d,n,p] = sum_c Wv[d,c] * xa[b,c,n,p]. grid (HW/256, NN, B).
__global__ void k_vproj(const float* __restrict__ xa, const float* __restrict__ W,
                        float* __restrict__ out) {
    const int p = blockIdx.x * 256 + threadIdx.x;
    const int n = blockIdx.y, b = blockIdx.z;
    const float* Wv = W + 2 * D * C;   // W[128:192] rows
    const float* xb = xa + ((size_t)(b * C) * NN + n) * HW + p;
    float xr[C];
#pragma unroll
    for (int c = 0; c < C; ++c) xr[c] = xb[(size_t)c * NN * HW];
    for (int d = 0; d < D; ++d) {
        float a = 0.f;
#pragma unroll
        for (int c = 0; c < C; ++c) a += Wv[d * C + c] * xr[c];
        out[((size_t)(b * D + d) * NN + n) * HW + p] = a;
    }
}

extern "C" void kernel_launch(void* const* d_in, const int* in_sizes, int n_in,
                              void* d_out, int out_size, void* d_ws, size_t ws_size,
                              hipStream_t stream) {
    const float* x = (const float*)d_in[0];
    const float* W = (const float*)d_in[1];
    float* outf = (float*)d_out;

    // ws: [ Q bf16 52.4MB | K bf16 52.4MB ], later reused as xa fp32 (104.86MB)
    ushort_t* Q  = (ushort_t*)d_ws;
    ushort_t* K  = Q + (size_t)B * NN * F;
    float*    xa = (float*)d_ws;

    // tiny accumulators live at head of d_out (dead until k_vproj rewrites all)
    float* S   = outf;          // 4*25*25
    float* qq  = outf + 2500;   // 4*25
    float* kk  = outf + 2600;   // 4*25
    float* att = outf + 2700;   // 4*25*25

    k_zero   <<<dim3(11),                  256, 0, stream>>>(outf);
    k_qkproj <<<dim3(HW/256, NN, B),       256, 0, stream>>>(x, W, Q, K, qq, kk);
    k_sqk    <<<dim3(F/(4*SW), B),         256, 0, stream>>>(Q, K, S);
    k_softmax<<<dim3(B),                    64, 0, stream>>>(S, qq, kk, att);
    k_mix    <<<dim3(HW/256, C, B),        256, 0, stream>>>(x, att, xa);
    k_vproj  <<<dim3(HW/256, NN, B),       256, 0, stream>>>(xa, W, outf);
}

// Round 3
// 564.614 us; speedup vs baseline: 3.3213x; 1.1336x over previous
//
#include <hip/hip_runtime.h>

// Problem constants (fixed by reference setup_inputs)
#define B   4
#define C   64      // input channels
#define D   64      // dims per head of q/k/v
#define NN  25      // angRes*angRes angular positions
#define HW  4096    // h*w
#define F   (D*HW)  // 262144 feature dim (d,h,w) flattened

#define SW  512     // f elems per wave in k_sqk (4 waves/block -> 2048 per block)

typedef unsigned short ushort_t;
typedef unsigned int   uint_t;
typedef __attribute__((ext_vector_type(8)))  short  short8;   // 8 bf16 (4 VGPRs)
typedef __attribute__((ext_vector_type(16))) float  floatx16; // MFMA 32x32 accum

static __device__ __forceinline__ ushort_t f2bf(float f) {
    uint_t u = __float_as_uint(f);
    u += 0x7FFFu + ((u >> 16) & 1u);   // round-to-nearest-even
    return (ushort_t)(u >> 16);
}

// ---- K0: zero the S/qq/kk accumulators (they live at head of d_out) ----
__global__ void k_zero(float* acc) {
    int i = blockIdx.x * 256 + threadIdx.x;
    if (i < 2700) acc[i] = 0.f;   // S 2500 + qq 100 + kk 100
}

// ---- K1: Q,K projection + fused norm accumulation.
// grid (HW/256, NN, B), 256 thr. Q[b][n][f], f = d*HW + p (reference flat()), bf16.
// __launch_bounds__(256,2): allow ~256 VGPR so xr[64] stays register-resident
// (default cap was 64 VGPR -> xr spilled to scratch -> 318us instead of ~70us).
__global__ void __launch_bounds__(256, 2)
k_qkproj(const float* __restrict__ x, const float* __restrict__ W,
         ushort_t* __restrict__ Q, ushort_t* __restrict__ K,
         float* __restrict__ qq, float* __restrict__ kk) {
    const int p = blockIdx.x * 256 + threadIdx.x;
    const int n = blockIdx.y, b = blockIdx.z;
    const float* xb = x + ((size_t)(b * C) * NN + n) * HW + p; // x[b][c][n][p]
    float xr[C];
#pragma unroll
    for (int c = 0; c < C; ++c) xr[c] = xb[(size_t)c * NN * HW];
    const float* Wq = W;            // W[0:64]   rows
    const float* Wk = W + D * C;    // W[64:128] rows
    const size_t obase = ((size_t)(b * NN + n) * D) * HW + p;
    float qn = 0.f, kn = 0.f;
    for (int d = 0; d < D; ++d) {
        float qa = 0.f, ka = 0.f;
#pragma unroll
        for (int c = 0; c < C; ++c) {
            qa += Wq[d * C + c] * xr[c];   // uniform row -> s_load_dwordx16
            ka += Wk[d * C + c] * xr[c];
        }
        qn += qa * qa; kn += ka * ka;      // fp32 norms, pre-rounding (matches ref)
        Q[obase + (size_t)d * HW] = f2bf(qa);
        K[obase + (size_t)d * HW] = f2bf(ka);
    }
    // wave-reduce the norm partials, one atomic per wave
    for (int off = 32; off > 0; off >>= 1) {
        qn += __shfl_xor(qn, off);
        kn += __shfl_xor(kn, off);
    }
    if ((threadIdx.x & 63) == 0) {
        atomicAdd(&qq[b * NN + n], qn);
        atomicAdd(&kk[b * NN + n], kn);
    }
}

// ---- K2: S[n][m] += sum_f Q[n,f]*K[m,f] via one 32x32x16 bf16 MFMA tile.
// grid (F/(4*SW), B), 256 thr = 4 waves, each wave owns SW f-elems.
// Pad rows/cols 25..31 clamp to 24: they only feed discarded output rows/cols.
__global__ void k_sqk(const ushort_t* __restrict__ Q, const ushort_t* __restrict__ K,
                      float* __restrict__ S) {
    const int t  = threadIdx.x;
    const int wv = t >> 6, ln = t & 63;
    const int b  = blockIdx.y;
    const int row  = ln & 31;
    const int rowc = (row < NN) ? row : (NN - 1);   // clamp pad rows
    const int kh   = (ln >> 5) * 8;                 // k-half offset
    const size_t f0 = (size_t)blockIdx.x * (4 * SW) + (size_t)wv * SW;
    const ushort_t* Qp = Q + ((size_t)b * NN + rowc) * F + f0 + kh;
    const ushort_t* Kp = K + ((size_t)b * NN + rowc) * F + f0 + kh;

    floatx16 acc;
#pragma unroll
    for (int r = 0; r < 16; ++r) acc[r] = 0.f;

    for (int s = 0; s < SW / 16; ++s) {
        short8 aq = *(const short8*)(Qp + s * 16);  // A[row][k] : 8 contig bf16
        short8 bk = *(const short8*)(Kp + s * 16);  // B[k][col] : K row 'col'
        acc = __builtin_amdgcn_mfma_f32_32x32x16_bf16(aq, bk, acc, 0, 0, 0);
    }

    // cross-wave reduce in LDS (stride 17 -> conflict-free), then atomics
    __shared__ float redS[4][64][17];
#pragma unroll
    for (int r = 0; r < 16; ++r) redS[wv][ln][r] = acc[r];
    __syncthreads();
    if (wv == 0) {
#pragma unroll
        for (int r = 0; r < 16; ++r) {
            float v = redS[0][ln][r] + redS[1][ln][r] + redS[2][ln][r] + redS[3][ln][r];
            const int srow = (r & 3) + 8 * (r >> 2) + 4 * (ln >> 5); // C/D: m74/m101
            const int scol = ln & 31;
            if (srow < NN && scol < NN)
                atomicAdd(&S[((size_t)b * NN + srow) * NN + scol], v);
        }
    }
}

// ---- K3: normalize logits + softmax over m. grid (B), 64 thr (25 active).
__global__ void k_softmax(const float* __restrict__ S, const float* __restrict__ qq,
                          const float* __restrict__ kk, float* __restrict__ att) {
    const int b = blockIdx.x, n = threadIdx.x;
    if (n >= NN) return;
    const float qn = fmaxf(sqrtf(qq[b * NN + n]), 1e-12f);
    float l[NN], mx = -1e30f;
#pragma unroll
    for (int m = 0; m < NN; ++m) {
        const float km = fmaxf(sqrtf(kk[b * NN + m]), 1e-12f);
        l[m] = S[((size_t)b * NN + n) * NN + m] / (qn * km);
        mx = fmaxf(mx, l[m]);
    }
    float s = 0.f;
#pragma unroll
    for (int m = 0; m < NN; ++m) { l[m] = expf(l[m] - mx); s += l[m]; }
    const float inv = 1.f / s;
#pragma unroll
    for (int m = 0; m < NN; ++m) att[((size_t)b * NN + n) * NN + m] = l[m] * inv;
}

// ---- K4a: xa[b,c,n,p] = sum_m att[n,m] * x[b,c,m,p]. grid (HW/256, C, B).
__global__ void __launch_bounds__(256, 4)
k_mix(const float* __restrict__ x, const float* __restrict__ att,
      float* __restrict__ xa) {
    const int p = blockIdx.x * 256 + threadIdx.x;
    const int c = blockIdx.y, b = blockIdx.z;
    const float* xb = x + ((size_t)(b * C + c) * NN) * HW + p;
    float xm[NN];
#pragma unroll
    for (int m = 0; m < NN; ++m) xm[m] = xb[(size_t)m * HW];
    const float* ab = att + (size_t)b * NN * NN;
    for (int n = 0; n < NN; ++n) {
        float a = 0.f;
#pragma unroll
        for (int m = 0; m < NN; ++m) a += ab[n * NN + m] * xm[m];  // att uniform -> s_load
        xa[((size_t)(b * C + c) * NN + n) * HW + p] = a;
    }
}

// ---- K4b: out[b,d,n,p] = sum_c Wv[d,c] * xa[b,c,n,p]. grid (HW/256, NN, B).
__global__ void __launch_bounds__(256, 2)
k_vproj(const float* __restrict__ xa, const float* __restrict__ W,
        float* __restrict__ out) {
    const int p = blockIdx.x * 256 + threadIdx.x;
    const int n = blockIdx.y, b = blockIdx.z;
    const float* Wv = W + 2 * D * C;   // W[128:192] rows
    const float* xb = xa + ((size_t)(b * C) * NN + n) * HW + p;
    float xr[C];
#pragma unroll
    for (int c = 0; c < C; ++c) xr[c] = xb[(size_t)c * NN * HW];
    for (int d = 0; d < D; ++d) {
        float a = 0.f;
#pragma unroll
        for (int c = 0; c < C; ++c) a += Wv[d * C + c] * xr[c];
        out[((size_t)(b * D + d) * NN + n) * HW + p] = a;
    }
}

extern "C" void kernel_launch(void* const* d_in, const int* in_sizes, int n_in,
                              void* d_out, int out_size, void* d_ws, size_t ws_size,
                              hipStream_t stream) {
    const float* x = (const float*)d_in[0];
    const float* W = (const float*)d_in[1];
    float* outf = (float*)d_out;

    // ws: [ Q bf16 52.4MB | K bf16 52.4MB ], later reused as xa fp32 (104.86MB)
    ushort_t* Q  = (ushort_t*)d_ws;
    ushort_t* K  = Q + (size_t)B * NN * F;
    float*    xa = (float*)d_ws;

    // tiny accumulators live at head of d_out (dead until k_vproj rewrites all)
    float* S   = outf;          // 4*25*25
    float* qq  = outf + 2500;   // 4*25
    float* kk  = outf + 2600;   // 4*25
    float* att = outf + 2700;   // 4*25*25

    k_zero   <<<dim3(11),                  256, 0, stream>>>(outf);
    k_qkproj <<<dim3(HW/256, NN, B),       256, 0, stream>>>(x, W, Q, K, qq, kk);
    k_sqk    <<<dim3(F/(4*SW), B),         256, 0, stream>>>(Q, K, S);
    k_softmax<<<dim3(B),                    64, 0, stream>>>(S, qq, kk, att);
    k_mix    <<<dim3(HW/256, C, B),        256, 0, stream>>>(x, att, xa);
    k_vproj  <<<dim3(HW/256, NN, B),       256, 0, stream>>>(xa, W, outf);
}

// Round 4
// 389.441 us; speedup vs baseline: 4.8152x; 1.4498x over previous
//
#include <hip/hip_runtime.h>

// Problem constants (fixed by reference setup_inputs)
#define B   4
#define C   64      // input channels
#define D   64      // dims per head of q/k/v
#define NN  25      // angRes*angRes angular positions
#define HW  4096    // h*w
#define F   (D*HW)  // 262144 feature dim (d,h,w) flattened

#define SW  1024    // f elems per wave in k_sqk (4 waves/block)

typedef unsigned short ushort_t;
typedef unsigned int   uint_t;
typedef __attribute__((ext_vector_type(8)))  short  short8;   // 8 bf16 (4 VGPRs)
typedef __attribute__((ext_vector_type(16))) float  floatx16; // MFMA 32x32 accum

// Transposed weights: Wt[c][d'] = W[d'][c] (d'<128: q rows then k rows),
// Wvt[c][d] = W[128+d][c]. Tiny, rewritten every launch (same work per call).
__device__ float g_Wt[C * 128];
__device__ float g_Wvt[C * 64];

static __device__ __forceinline__ ushort_t f2bf(float f) {
    uint_t u = __float_as_uint(f);
    u += 0x7FFFu + ((u >> 16) & 1u);   // round-to-nearest-even
    return (ushort_t)(u >> 16);
}

// ---- K0: zero the S/qq/kk accumulators (they live at head of d_out) ----
__global__ void k_zero(float* acc) {
    int i = blockIdx.x * 256 + threadIdx.x;
    if (i < 2700) acc[i] = 0.f;   // S 2500 + qq 100 + kk 100
}

// ---- Kw: transpose W into g_Wt / g_Wvt. 48 blocks x 256 thr. ----
__global__ void k_wprep(const float* __restrict__ W) {
    int i = blockIdx.x * 256 + threadIdx.x;          // over 192*64
    if (i < 128 * 64) {
        int dp = i >> 6, c = i & 63;
        g_Wt[c * 128 + dp] = W[dp * 64 + c];
    } else if (i < 192 * 64) {
        int j = i - 128 * 64;
        int d = j >> 6, c = j & 63;
        g_Wvt[c * 64 + d] = W[(128 + d) * 64 + c];
    }
}

// ---- K1: Q,K projection, accumulator form (remat-proof) + fused norms.
// grid (HW/256, NN, B), 256 thr. acc[128] stays in VGPRs: it is WRITTEN every
// c-iter, so the register allocator cannot rematerialize it (the round-3
// xr[64] version got its invariant loads remat'd -> 64x L2 re-read of x).
__global__ void __launch_bounds__(256, 2)
k_qkproj(const float* __restrict__ x,
         ushort_t* __restrict__ Q, ushort_t* __restrict__ K,
         float* __restrict__ qq, float* __restrict__ kk) {
    const int p = blockIdx.x * 256 + threadIdx.x;
    const int n = blockIdx.y, b = blockIdx.z;
    const float* xb = x + ((size_t)(b * C) * NN + n) * HW + p; // x[b][c][n][p]

    float acc[128];
#pragma unroll
    for (int i = 0; i < 128; ++i) acc[i] = 0.f;

#pragma unroll 2
    for (int c = 0; c < C; ++c) {
        const float xc = xb[(size_t)c * NN * HW];   // used once -> no remat win
        const float* wr = g_Wt + c * 128;           // contiguous -> s_load_dwordx16
#pragma unroll
        for (int dp = 0; dp < 128; ++dp) acc[dp] += wr[dp] * xc;
    }

    const size_t obase = ((size_t)(b * NN + n) * D) * HW + p;
    float qn = 0.f, kn = 0.f;
#pragma unroll
    for (int d = 0; d < D; ++d) {
        qn += acc[d] * acc[d];
        kn += acc[64 + d] * acc[64 + d];            // fp32 pre-rounding norms
        Q[obase + (size_t)d * HW] = f2bf(acc[d]);
        K[obase + (size_t)d * HW] = f2bf(acc[64 + d]);
    }
    for (int off = 32; off > 0; off >>= 1) {
        qn += __shfl_xor(qn, off);
        kn += __shfl_xor(kn, off);
    }
    if ((threadIdx.x & 63) == 0) {
        atomicAdd(&qq[b * NN + n], qn);
        atomicAdd(&kk[b * NN + n], kn);
    }
}

// ---- K2: S[n][m] += sum_f Q[n,f]*K[m,f] via one 32x32x16 bf16 MFMA tile.
// grid (F/(4*SW), B), 256 thr = 4 waves, each wave owns SW f-elems.
// Pad rows/cols 25..31 clamp to 24: they only feed discarded output rows/cols.
__global__ void k_sqk(const ushort_t* __restrict__ Q, const ushort_t* __restrict__ K,
                      float* __restrict__ S) {
    const int t  = threadIdx.x;
    const int wv = t >> 6, ln = t & 63;
    const int b  = blockIdx.y;
    const int row  = ln & 31;
    const int rowc = (row < NN) ? row : (NN - 1);   // clamp pad rows
    const int kh   = (ln >> 5) * 8;                 // k-half offset
    const size_t f0 = (size_t)blockIdx.x * (4 * SW) + (size_t)wv * SW;
    const ushort_t* Qp = Q + ((size_t)b * NN + rowc) * F + f0 + kh;
    const ushort_t* Kp = K + ((size_t)b * NN + rowc) * F + f0 + kh;

    floatx16 acc;
#pragma unroll
    for (int r = 0; r < 16; ++r) acc[r] = 0.f;

    for (int s = 0; s < SW / 16; ++s) {
        short8 aq = *(const short8*)(Qp + s * 16);  // A[row][k] : 8 contig bf16
        short8 bk = *(const short8*)(Kp + s * 16);  // B[k][col] : K row 'col'
        acc = __builtin_amdgcn_mfma_f32_32x32x16_bf16(aq, bk, acc, 0, 0, 0);
    }

    // cross-wave reduce in LDS (stride 17 -> conflict-free), then atomics
    __shared__ float redS[4][64][17];
#pragma unroll
    for (int r = 0; r < 16; ++r) redS[wv][ln][r] = acc[r];
    __syncthreads();
    if (wv == 0) {
#pragma unroll
        for (int r = 0; r < 16; ++r) {
            float v = redS[0][ln][r] + redS[1][ln][r] + redS[2][ln][r] + redS[3][ln][r];
            const int srow = (r & 3) + 8 * (r >> 2) + 4 * (ln >> 5); // C/D: m74/m101
            const int scol = ln & 31;
            if (srow < NN && scol < NN)
                atomicAdd(&S[((size_t)b * NN + srow) * NN + scol], v);
        }
    }
}

// ---- K3: normalize logits + softmax over m; writes TRANSPOSED att.
// attT[b][m][n] so k_mix's scalar reads are contiguous. grid (B), 64 thr.
__global__ void k_softmax(const float* __restrict__ S, const float* __restrict__ qq,
                          const float* __restrict__ kk, float* __restrict__ attT) {
    const int b = blockIdx.x, n = threadIdx.x;
    if (n >= NN) return;
    const float qn = fmaxf(sqrtf(qq[b * NN + n]), 1e-12f);
    float l[NN], mx = -1e30f;
#pragma unroll
    for (int m = 0; m < NN; ++m) {
        const float km = fmaxf(sqrtf(kk[b * NN + m]), 1e-12f);
        l[m] = S[((size_t)b * NN + n) * NN + m] / (qn * km);
        mx = fmaxf(mx, l[m]);
    }
    float s = 0.f;
#pragma unroll
    for (int m = 0; m < NN; ++m) { l[m] = expf(l[m] - mx); s += l[m]; }
    const float inv = 1.f / s;
#pragma unroll
    for (int m = 0; m < NN; ++m) attT[((size_t)b * NN + m) * NN + n] = l[m] * inv;
}

// ---- K4a: xa[b,c,n,p] = sum_m att[n,m] * x[b,c,m,p], accumulator form.
// grid (HW/256, C, B). acc[25] written every m-iter -> register-resident.
__global__ void k_mix(const float* __restrict__ x, const float* __restrict__ attT,
                      float* __restrict__ xa) {
    const int p = blockIdx.x * 256 + threadIdx.x;
    const int c = blockIdx.y, b = blockIdx.z;
    const float* xb = x + ((size_t)(b * C + c) * NN) * HW + p;
    const float* at = attT + (size_t)b * NN * NN;
    float acc[NN];
#pragma unroll
    for (int n = 0; n < NN; ++n) acc[n] = 0.f;
#pragma unroll 5
    for (int m = 0; m < NN; ++m) {
        const float xm = xb[(size_t)m * HW];
#pragma unroll
        for (int n = 0; n < NN; ++n) acc[n] += at[m * NN + n] * xm; // contig s_load
    }
#pragma unroll
    for (int n = 0; n < NN; ++n)
        xa[((size_t)(b * C + c) * NN + n) * HW + p] = acc[n];
}

// ---- K4b: out[b,d,n,p] = sum_c Wv[d,c] * xa[b,c,n,p], accumulator form.
// grid (HW/256, NN, B). acc[64] register-resident; Wvt rows via s_load.
__global__ void __launch_bounds__(256, 4)
k_vproj(const float* __restrict__ xa, float* __restrict__ out) {
    const int p = blockIdx.x * 256 + threadIdx.x;
    const int n = blockIdx.y, b = blockIdx.z;
    const float* xb = xa + ((size_t)(b * C) * NN + n) * HW + p;

    float acc[D];
#pragma unroll
    for (int d = 0; d < D; ++d) acc[d] = 0.f;

#pragma unroll 2
    for (int c = 0; c < C; ++c) {
        const float xc = xb[(size_t)c * NN * HW];
        const float* wr = g_Wvt + c * 64;           // contiguous -> s_load_dwordx16
#pragma unroll
        for (int d = 0; d < D; ++d) acc[d] += wr[d] * xc;
    }
#pragma unroll
    for (int d = 0; d < D; ++d)
        out[((size_t)(b * D + d) * NN + n) * HW + p] = acc[d];
}

extern "C" void kernel_launch(void* const* d_in, const int* in_sizes, int n_in,
                              void* d_out, int out_size, void* d_ws, size_t ws_size,
                              hipStream_t stream) {
    const float* x = (const float*)d_in[0];
    const float* W = (const float*)d_in[1];
    float* outf = (float*)d_out;

    // ws: [ Q bf16 52.4MB | K bf16 52.4MB ], later reused as xa fp32 (104.86MB)
    ushort_t* Q  = (ushort_t*)d_ws;
    ushort_t* K  = Q + (size_t)B * NN * F;
    float*    xa = (float*)d_ws;

    // tiny accumulators live at head of d_out (dead until k_vproj rewrites all)
    float* S    = outf;          // 4*25*25
    float* qq   = outf + 2500;   // 4*25
    float* kk   = outf + 2600;   // 4*25
    float* attT = outf + 2700;   // 4*25*25 (transposed: [b][m][n])

    k_zero   <<<dim3(11),            256, 0, stream>>>(outf);
    k_wprep  <<<dim3(48),            256, 0, stream>>>(W);
    k_qkproj <<<dim3(HW/256, NN, B), 256, 0, stream>>>(x, Q, K, qq, kk);
    k_sqk    <<<dim3(F/(4*SW), B),   256, 0, stream>>>(Q, K, S);
    k_softmax<<<dim3(B),              64, 0, stream>>>(S, qq, kk, attT);
    k_mix    <<<dim3(HW/256, C, B),  256, 0, stream>>>(x, attT, xa);
    k_vproj  <<<dim3(HW/256, NN, B), 256, 0, stream>>>(xa, outf);
}